// Round 4
// baseline (463.729 us; speedup 1.0000x reference)
//
#include <hip/hip_runtime.h>
#include <hip/hip_cooperative_groups.h>
#include <cstdint>
#include <cstddef>

namespace cg = cooperative_groups;

// Problem dims (fixed by setup_inputs): b=4096, d=n=1024, k=4
#define NB 4096
#define ND 1024

typedef unsigned short ushortT;
typedef short short8 __attribute__((ext_vector_type(8)));
typedef float f32x4 __attribute__((ext_vector_type(4)));

struct Params {
    const float *x, *mu1, *lam1, *v1, *g1, *b1, *mu2, *lam2, *v2, *g2, *b2;
    float* out;
    ushortT *xh, *W1, *W2, *hh, *U1;
    float *U2;
    float *xx1, *xx2, *mm1, *mm2, *vmu1, *vmu2;
    float *sum1, *sumsq1, *sum2, *sumsq2;
};

__device__ __forceinline__ ushortT f2bf(float f) {
    unsigned u = __float_as_uint(f);
    u += 0x7FFFu + ((u >> 16) & 1u);      // round-to-nearest-even
    return (ushortT)(u >> 16);
}
__device__ __forceinline__ float bf2f(ushortT b) {
    return __uint_as_float(((unsigned)b) << 16);
}
__device__ __forceinline__ float wave_sum(float v) {
    #pragma unroll
    for (int o = 1; o < 64; o <<= 1) v += __shfl_xor(v, o, 64);
    return v;
}

// ---- phase 0: prep (wave-per-row, no block barriers) ------------------------
__device__ __forceinline__ void prep_row_x(const float* __restrict__ row,
                                           ushortT* __restrict__ orow,
                                           float* __restrict__ dst, int l) {
    float s = 0.f;
    #pragma unroll
    for (int j = 0; j < 4; ++j) {
        int c = (j * 64 + l) * 4;
        float4 xv = *reinterpret_cast<const float4*>(row + c);
        ushortT b0 = f2bf(xv.x), b1 = f2bf(xv.y), b2 = f2bf(xv.z), b3 = f2bf(xv.w);
        *reinterpret_cast<ushort4*>(orow + c) = make_ushort4(b0, b1, b2, b3);
        float r0 = bf2f(b0), r1 = bf2f(b1), r2 = bf2f(b2), r3 = bf2f(b3);
        s += r0 * r0 + r1 * r1 + r2 * r2 + r3 * r3;
    }
    s = wave_sum(s);
    if (l == 0) *dst = s;
}

__device__ __forceinline__ void prep_row_w(const float* __restrict__ src,
                                           const float* __restrict__ murow,
                                           ushortT* __restrict__ dst,
                                           float* __restrict__ res, int l) {
    float s = 0.f;
    #pragma unroll
    for (int j = 0; j < 4; ++j) {
        int c = (j * 64 + l) * 4;
        float4 sv = *reinterpret_cast<const float4*>(src + c);
        float4 mv = *reinterpret_cast<const float4*>(murow + c);
        ushortT b0 = f2bf(sv.x), b1 = f2bf(sv.y), b2 = f2bf(sv.z), b3 = f2bf(sv.w);
        *reinterpret_cast<ushort4*>(dst + c) = make_ushort4(b0, b1, b2, b3);
        s += bf2f(b0) * bf2f(f2bf(mv.x)) + bf2f(b1) * bf2f(f2bf(mv.y))
           + bf2f(b2) * bf2f(f2bf(mv.z)) + bf2f(b3) * bf2f(f2bf(mv.w));
    }
    s = wave_sum(s);
    if (l == 0) *res = s;
}

__device__ __forceinline__ void prep_phase(const Params& P, int gw, int nw, int l) {
    // zero the 4x1024 contiguous BN stat accumulators
    for (int i = blockIdx.x * 256 + threadIdx.x; i < 4096; i += gridDim.x * 256)
        P.sum1[i] = 0.f;
    for (int task = gw; task < 14336; task += nw) {
        if (task < 4096) {
            prep_row_x(P.x + (size_t)task * ND, P.xh + (size_t)task * ND, P.xx1 + task, l);
        } else {
            int tt = task - 4096;
            int layer = tt >= 5120 ? 1 : 0;
            int within = layer ? tt - 5120 : tt;
            int t = within >> 10, n = within & 1023;
            const float* mu = layer ? P.mu2 : P.mu1;
            const float* v  = layer ? P.v2  : P.v1;
            ushortT* W      = layer ? P.W2  : P.W1;
            float* mm       = layer ? P.mm2 : P.mm1;
            float* vmu      = layer ? P.vmu2 : P.vmu1;
            const float* src = (t == 0) ? (mu + (size_t)n * ND)
                                        : (v + ((size_t)n * 4 + (t - 1)) * ND);
            float* res = (t == 0) ? (mm + n) : (vmu + n * 4 + (t - 1));
            prep_row_w(src, mu + (size_t)n * ND, W + ((size_t)t * 1024 + n) * ND, res, l);
        }
    }
}

// ---- GEMM phase: round-2 structure (proven 46.8us/dispatch) -----------------
// Tile 128(M) x 64(n) x 5 panels, BK=64, 4 waves, 56KB static LDS, grid-stride
// over the 512 tiles. XOR slot swizzle s = p ^ (row&7): linear LDS dest,
// inverse-swizzled global source, swizzled ds_read (rule #21 pair).
template <int STORE_BF16>
__device__ __forceinline__ void gemm_phase(
    ushortT* As, ushortT* Bs,
    const ushortT* __restrict__ Xh, const ushortT* __restrict__ Wh,
    const float* __restrict__ xx, const float* __restrict__ mm,
    const float* __restrict__ vmu, const float* __restrict__ lam,
    ushortT* __restrict__ Ub, float* __restrict__ Uf,
    float* __restrict__ sum, float* __restrict__ sumsq)
{
    const int tid = threadIdx.x;
    const int lane = tid & 63, wave = tid >> 6;
    const int lrow8 = lane >> 3;       // row within an 8-row chunk
    const int lp    = lane & 7;        // linear 16B slot within the row

    for (int tile = blockIdx.x; tile < 512; tile += gridDim.x) {
        const int n0 = (tile & 15) * 64;
        const int m0 = (tile >> 4) * 128;

        f32x4 acc[8][5];
        #pragma unroll
        for (int mf = 0; mf < 8; ++mf)
            #pragma unroll
            for (int t = 0; t < 5; ++t)
                acc[mf][t] = (f32x4){0.f, 0.f, 0.f, 0.f};

        for (int kt = 0; kt < 16; ++kt) {
            const int k0 = kt * 64;
            #pragma unroll
            for (int q = 0; q < 4; ++q) {          // A: 16 chunks of 1KB
                int chunk = q * 4 + wave;
                int row = chunk * 8 + lrow8;
                int s = lp ^ (row & 7);
                const ushortT* src = Xh + (size_t)(m0 + row) * ND + k0 + s * 8;
                __builtin_amdgcn_global_load_lds(
                    (const __attribute__((address_space(1))) void*)src,
                    (__attribute__((address_space(3))) void*)(As + chunk * 512), 16, 0, 0);
            }
            #pragma unroll
            for (int q = 0; q < 10; ++q) {         // B: 40 chunks (5 panels x 64 rows)
                int chunk = q * 4 + wave;
                int row = chunk * 8 + lrow8;       // 0..319
                int t = row >> 6, rr = row & 63;
                int s = lp ^ (row & 7);
                const ushortT* src = Wh + ((size_t)t * 1024 + n0 + rr) * ND + k0 + s * 8;
                __builtin_amdgcn_global_load_lds(
                    (const __attribute__((address_space(1))) void*)src,
                    (__attribute__((address_space(3))) void*)(Bs + chunk * 512), 16, 0, 0);
            }
            __syncthreads();
            #pragma unroll
            for (int i = 0; i < 2; ++i) {          // two K=32 substeps
                short8 av[8];
                #pragma unroll
                for (int mf = 0; mf < 8; ++mf) {
                    int row = mf * 16 + (lane & 15);
                    int sl = (4 * i + (lane >> 4)) ^ (row & 7);
                    av[mf] = *reinterpret_cast<const short8*>(&As[row * 64 + sl * 8]);
                }
                #pragma unroll
                for (int t = 0; t < 5; ++t) {
                    int rr = wave * 16 + (lane & 15);
                    int sl = (4 * i + (lane >> 4)) ^ (rr & 7);
                    short8 bv = *reinterpret_cast<const short8*>(&Bs[(t * 64 + rr) * 64 + sl * 8]);
                    #pragma unroll
                    for (int mf = 0; mf < 8; ++mf)
                        acc[mf][t] = __builtin_amdgcn_mfma_f32_16x16x32_bf16(av[mf], bv, acc[mf][t], 0, 0, 0);
                }
            }
            __syncthreads();
        }

        // epilogue: u = expm1(-q/1024) cubic; fused column stats
        const int col = n0 + wave * 16 + (lane & 15);
        const float lamc = lam[col], mmc = mm[col];
        const float4 vm = *reinterpret_cast<const float4*>(vmu + col * 4);
        float csum = 0.f, csq = 0.f;
        #pragma unroll
        for (int mf = 0; mf < 8; ++mf) {
            #pragma unroll
            for (int i = 0; i < 4; ++i) {
                int brow = m0 + mf * 16 + (lane >> 4) * 4 + i;
                float s0 = acc[mf][0][i];
                float p0 = acc[mf][1][i] - vm.x;
                float p1 = acc[mf][2][i] - vm.y;
                float p2 = acc[mf][3][i] - vm.z;
                float p3 = acc[mf][4][i] - vm.w;
                float q = lamc * (xx[brow] - 2.f * s0 + mmc)
                        + p0 * p0 + p1 * p1 + p2 * p2 + p3 * p3;
                float xq = q * (1.0f / 1024.0f);
                float u = -xq * (1.0f - xq * (0.5f - xq * 0.16666667f));  // expm1(-x)
                float ur;
                if (STORE_BF16) {
                    ushortT ub = f2bf(u);
                    Ub[(size_t)brow * ND + col] = ub;
                    ur = bf2f(ub);
                } else {
                    Uf[(size_t)brow * ND + col] = u;
                    ur = u;
                }
                csum += ur; csq += ur * ur;
            }
        }
        csum += __shfl_xor(csum, 16); csum += __shfl_xor(csum, 32);
        csq  += __shfl_xor(csq, 16);  csq  += __shfl_xor(csq, 32);
        if (lane < 16) {
            atomicAdd(&sum[col], csum);
            atomicAdd(&sumsq[col], csq);
        }
    }
}

// ---- BN1 apply -> h (bf16) + post-round row norms (wave-per-row) ------------
__device__ __forceinline__ void bnh_phase(const Params& P, int gw, int nw, int l) {
    for (int row = gw; row < NB; row += nw) {
        const ushortT* urow = P.U1 + (size_t)row * ND;
        ushortT* hrow = P.hh + (size_t)row * ND;
        float s = 0.f;
        #pragma unroll
        for (int j = 0; j < 4; ++j) {
            int c = (j * 64 + l) * 4;
            ushort4 uv = *reinterpret_cast<const ushort4*>(urow + c);
            float4 sv = *reinterpret_cast<const float4*>(P.sum1 + c);
            float4 qv = *reinterpret_cast<const float4*>(P.sumsq1 + c);
            float4 gv = *reinterpret_cast<const float4*>(P.g1 + c);
            float4 bv = *reinterpret_cast<const float4*>(P.b1 + c);
            float ua[4] = {bf2f(uv.x), bf2f(uv.y), bf2f(uv.z), bf2f(uv.w)};
            float sa[4] = {sv.x, sv.y, sv.z, sv.w};
            float qa[4] = {qv.x, qv.y, qv.z, qv.w};
            float ga[4] = {gv.x, gv.y, gv.z, gv.w};
            float ba[4] = {bv.x, bv.y, bv.z, bv.w};
            ushortT hb[4];
            #pragma unroll
            for (int e = 0; e < 4; ++e) {
                float m = sa[e] * (1.0f / 4096.0f);
                float var = qa[e] * (1.0f / 4096.0f) - m * m;
                float a = rsqrtf(var + 1e-5f) * ga[e];
                float h = (ua[e] - m) * a + ba[e];
                hb[e] = f2bf(h);
                float hr = bf2f(hb[e]);
                s += hr * hr;
            }
            *reinterpret_cast<ushort4*>(hrow + c) = make_ushort4(hb[0], hb[1], hb[2], hb[3]);
        }
        s = wave_sum(s);
        if (l == 0) P.xx2[row] = s;
    }
}

// ---- BN2 apply + identity shortcut (wave-per-row) ---------------------------
__device__ __forceinline__ void bnout_phase(const Params& P, int gw, int nw, int l) {
    for (int row = gw; row < NB; row += nw) {
        const float* urow = P.U2 + (size_t)row * ND;
        const float* xrow = P.x + (size_t)row * ND;
        float* orow = P.out + (size_t)row * ND;
        #pragma unroll
        for (int j = 0; j < 4; ++j) {
            int c = (j * 64 + l) * 4;
            float4 uv = *reinterpret_cast<const float4*>(urow + c);
            float4 xv = *reinterpret_cast<const float4*>(xrow + c);
            float4 sv = *reinterpret_cast<const float4*>(P.sum2 + c);
            float4 qv = *reinterpret_cast<const float4*>(P.sumsq2 + c);
            float4 gv = *reinterpret_cast<const float4*>(P.g2 + c);
            float4 bv = *reinterpret_cast<const float4*>(P.b2 + c);
            float4 ov;
            {
                float m = sv.x * (1.0f/4096.0f), var = qv.x * (1.0f/4096.0f) - m*m;
                float a = rsqrtf(var + 1e-5f) * gv.x; ov.x = (uv.x - m) * a + bv.x + xv.x;
            }
            {
                float m = sv.y * (1.0f/4096.0f), var = qv.y * (1.0f/4096.0f) - m*m;
                float a = rsqrtf(var + 1e-5f) * gv.y; ov.y = (uv.y - m) * a + bv.y + xv.y;
            }
            {
                float m = sv.z * (1.0f/4096.0f), var = qv.z * (1.0f/4096.0f) - m*m;
                float a = rsqrtf(var + 1e-5f) * gv.z; ov.z = (uv.z - m) * a + bv.z + xv.z;
            }
            {
                float m = sv.w * (1.0f/4096.0f), var = qv.w * (1.0f/4096.0f) - m*m;
                float a = rsqrtf(var + 1e-5f) * gv.w; ov.w = (uv.w - m) * a + bv.w + xv.w;
            }
            *reinterpret_cast<float4*>(orow + c) = ov;
        }
    }
}

// ---- the whole pipeline as one cooperative kernel ---------------------------
__global__ __launch_bounds__(256, 2) void hmu_mono(Params P) {
    __shared__ ushortT As[128 * 64];     // 16 KB
    __shared__ ushortT Bs[5 * 64 * 64];  // 40 KB
    cg::grid_group grid = cg::this_grid();

    const int gw = (blockIdx.x * 256 + threadIdx.x) >> 6;
    const int nw = (gridDim.x * 256) >> 6;
    const int l = threadIdx.x & 63;

    prep_phase(P, gw, nw, l);
    grid.sync(); __threadfence();
    gemm_phase<1>(As, Bs, P.xh, P.W1, P.xx1, P.mm1, P.vmu1, P.lam1,
                  P.U1, nullptr, P.sum1, P.sumsq1);
    grid.sync(); __threadfence();
    bnh_phase(P, gw, nw, l);
    grid.sync(); __threadfence();
    gemm_phase<0>(As, Bs, P.hh, P.W2, P.xx2, P.mm2, P.vmu2, P.lam2,
                  nullptr, P.U2, P.sum2, P.sumsq2);
    grid.sync(); __threadfence();
    bnout_phase(P, gw, nw, l);
}

extern "C" void kernel_launch(void* const* d_in, const int* in_sizes, int n_in,
                              void* d_out, int out_size, void* d_ws, size_t ws_size,
                              hipStream_t stream) {
    char* ws = (char*)d_ws;
    const size_t MB = 1024 * 1024;

    // workspace layout (lifetime-overlapped):
    // [0,8)MB xh ; [8,18)MB W1 ; U2(f32,16MB) aliases [0,16) after gemm1 retires xh/W1
    // [18,26)MB hh ; [26,36)MB W2 ; [36,44)MB U1(bf16) ; [44MB,..) stats
    Params P;
    P.x    = (const float*)d_in[0];
    P.mu1  = (const float*)d_in[1];
    P.lam1 = (const float*)d_in[2];
    P.v1   = (const float*)d_in[3];
    P.g1   = (const float*)d_in[4];
    P.b1   = (const float*)d_in[5];
    P.mu2  = (const float*)d_in[6];
    P.lam2 = (const float*)d_in[7];
    P.v2   = (const float*)d_in[8];
    P.g2   = (const float*)d_in[9];
    P.b2   = (const float*)d_in[10];
    P.out  = (float*)d_out;
    P.xh   = (ushortT*)(ws + 0);
    P.W1   = (ushortT*)(ws + 8 * MB);
    P.U2   = (float*)  (ws + 0);
    P.hh   = (ushortT*)(ws + 18 * MB);
    P.W2   = (ushortT*)(ws + 26 * MB);
    P.U1   = (ushortT*)(ws + 36 * MB);
    char* st = ws + 44 * MB;
    P.xx1    = (float*)(st + 0);
    P.xx2    = (float*)(st + 16384);
    P.mm1    = (float*)(st + 32768);
    P.mm2    = (float*)(st + 36864);
    P.vmu1   = (float*)(st + 40960);
    P.vmu2   = (float*)(st + 57344);
    P.sum1   = (float*)(st + 73728);   // sum1,sumsq1,sum2,sumsq2 contiguous 16KB
    P.sumsq1 = (float*)(st + 77824);
    P.sum2   = (float*)(st + 81920);
    P.sumsq2 = (float*)(st + 86016);

    const size_t needed = 44 * MB + 90112;
    if (ws_size < needed) return;

    int maxb = 0;
    hipOccupancyMaxActiveBlocksPerMultiprocessor(&maxb, (const void*)hmu_mono, 256, 0);
    if (maxb < 1) maxb = 1;
    int grid = maxb >= 2 ? 512 : 256;   // must be fully co-resident on 256 CUs

    void* kargs[] = { (void*)&P };
    hipLaunchCooperativeKernel((const void*)hmu_mono, dim3(grid), dim3(256),
                               kargs, 0, stream);
}

// Round 5
// 206.503 us; speedup vs baseline: 2.2456x; 2.2456x over previous
//
#include <hip/hip_runtime.h>
#include <cstdint>
#include <cstddef>

// Problem dims (fixed by setup_inputs): b=4096, d=n=1024, k=4
#define NB 4096
#define ND 1024

typedef unsigned short ushortT;
typedef short short8 __attribute__((ext_vector_type(8)));
typedef float f32x4 __attribute__((ext_vector_type(4)));

__device__ __forceinline__ ushortT f2bf(float f) {
    unsigned u = __float_as_uint(f);
    u += 0x7FFFu + ((u >> 16) & 1u);      // round-to-nearest-even
    return (ushortT)(u >> 16);
}
__device__ __forceinline__ float bf2f(ushortT b) {
    return __uint_as_float(((unsigned)b) << 16);
}
__device__ __forceinline__ float wave_sum(float v) {
    #pragma unroll
    for (int o = 1; o < 64; o <<= 1) v += __shfl_xor(v, o, 64);
    return v;
}

// --- prep: wave-per-row, no block barriers -----------------------------------
// grid 3584 x 256 thr = 14336 waves; wave w = task w.
// task < 4096:  x row -> bf16 + post-round ||x||^2
// else: W row (layer, panel t, col n) -> bf16 + ||mu||^2 / v.mu
// Also zeroes the 4x1024 BN stat accumulators (16KB contiguous at sum1).
__global__ void prep_all(const float* __restrict__ x,
                         const float* __restrict__ mu1, const float* __restrict__ v1,
                         const float* __restrict__ mu2, const float* __restrict__ v2,
                         ushortT* __restrict__ xh, ushortT* __restrict__ W1,
                         ushortT* __restrict__ W2,
                         float* __restrict__ xx1,
                         float* __restrict__ mm1, float* __restrict__ vmu1,
                         float* __restrict__ mm2, float* __restrict__ vmu2,
                         float* __restrict__ statz) {
    const int gid = blockIdx.x * 256 + threadIdx.x;
    if (gid < 4096) statz[gid] = 0.f;
    const int task = gid >> 6;
    const int l = gid & 63;
    if (task < 4096) {
        const float* row = x + (size_t)task * ND;
        ushortT* orow = xh + (size_t)task * ND;
        float s = 0.f;
        #pragma unroll
        for (int j = 0; j < 4; ++j) {
            int c = (j * 64 + l) * 4;
            float4 xv = *reinterpret_cast<const float4*>(row + c);
            ushortT b0 = f2bf(xv.x), b1 = f2bf(xv.y), b2 = f2bf(xv.z), b3 = f2bf(xv.w);
            *reinterpret_cast<ushort4*>(orow + c) = make_ushort4(b0, b1, b2, b3);
            float r0 = bf2f(b0), r1 = bf2f(b1), r2 = bf2f(b2), r3 = bf2f(b3);
            s += r0 * r0 + r1 * r1 + r2 * r2 + r3 * r3;
        }
        s = wave_sum(s);
        if (l == 0) xx1[task] = s;
    } else {
        int tt = task - 4096;
        const int layer = tt >= 5120;
        if (layer) tt -= 5120;
        const float* mu = layer ? mu2 : mu1;
        const float* v  = layer ? v2  : v1;
        ushortT* W      = layer ? W2  : W1;
        float* mm       = layer ? mm2 : mm1;
        float* vmu      = layer ? vmu2 : vmu1;
        const int t = tt >> 10, n = tt & 1023;
        const float* src = (t == 0) ? (mu + (size_t)n * ND)
                                    : (v + ((size_t)n * 4 + (t - 1)) * ND);
        const float* murow = mu + (size_t)n * ND;
        ushortT* dst = W + ((size_t)t * 1024 + n) * ND;
        float s = 0.f;
        #pragma unroll
        for (int j = 0; j < 4; ++j) {
            int c = (j * 64 + l) * 4;
            float4 sv = *reinterpret_cast<const float4*>(src + c);
            float4 mv = *reinterpret_cast<const float4*>(murow + c);
            ushortT b0 = f2bf(sv.x), b1 = f2bf(sv.y), b2 = f2bf(sv.z), b3 = f2bf(sv.w);
            *reinterpret_cast<ushort4*>(dst + c) = make_ushort4(b0, b1, b2, b3);
            s += bf2f(b0) * bf2f(f2bf(mv.x)) + bf2f(b1) * bf2f(f2bf(mv.y))
               + bf2f(b2) * bf2f(f2bf(mv.z)) + bf2f(b3) * bf2f(f2bf(mv.w));
        }
        s = wave_sum(s);
        if (l == 0) {
            if (t == 0) mm[n] = s;
            else        vmu[n * 4 + (t - 1)] = s;
        }
    }
}

// --- fused 5-panel HMU GEMM + column stats (round-2 structure, proven) -------
// Tile: 128(M) x 64(n) x 5 panels, BK=64, 4 waves, 56KB static LDS, 2 blk/CU.
// Wave w owns ALL 128 rows x 16 n-cols x 5 panels: acc[mf][t], mf<8, t<5.
// Staging: global_load_lds width 16, linear LDS dest, inverse-XOR-swizzled
// global source (slot s = p ^ (row&7), involution), swizzled ds_read.
template <int STORE_BF16>
__launch_bounds__(256, 2)
__global__ void gemm_hmu(const ushortT* __restrict__ Xh, const ushortT* __restrict__ Wh,
                         const float* __restrict__ xx, const float* __restrict__ mm,
                         const float* __restrict__ vmu, const float* __restrict__ lam,
                         ushortT* __restrict__ Ub, float* __restrict__ Uf,
                         float* __restrict__ sum, float* __restrict__ sumsq) {
    __shared__ ushortT As[128 * 64];        // 16 KB
    __shared__ ushortT Bs[5 * 64 * 64];     // 40 KB
    const int tid = threadIdx.x;
    const int lane = tid & 63, wave = tid >> 6;
    const int n0 = (blockIdx.x & 15) * 64;
    const int m0 = (blockIdx.x >> 4) * 128;

    f32x4 acc[8][5];
    #pragma unroll
    for (int mf = 0; mf < 8; ++mf)
        #pragma unroll
        for (int t = 0; t < 5; ++t)
            acc[mf][t] = (f32x4){0.f, 0.f, 0.f, 0.f};

    const int lrow8 = lane >> 3;       // row within an 8-row chunk
    const int lp    = lane & 7;        // linear 16B slot within the row

    for (int kt = 0; kt < 16; ++kt) {
        const int k0 = kt * 64;
        #pragma unroll
        for (int q = 0; q < 4; ++q) {          // A: 16 chunks of 1KB
            int chunk = q * 4 + wave;
            int row = chunk * 8 + lrow8;
            int s = lp ^ (row & 7);
            const ushortT* src = Xh + (size_t)(m0 + row) * ND + k0 + s * 8;
            __builtin_amdgcn_global_load_lds(
                (const __attribute__((address_space(1))) void*)src,
                (__attribute__((address_space(3))) void*)(As + chunk * 512), 16, 0, 0);
        }
        #pragma unroll
        for (int q = 0; q < 10; ++q) {         // B: 40 chunks (5 panels x 64 rows)
            int chunk = q * 4 + wave;
            int row = chunk * 8 + lrow8;       // 0..319
            int t = row >> 6, rr = row & 63;
            int s = lp ^ (row & 7);
            const ushortT* src = Wh + ((size_t)t * 1024 + n0 + rr) * ND + k0 + s * 8;
            __builtin_amdgcn_global_load_lds(
                (const __attribute__((address_space(1))) void*)src,
                (__attribute__((address_space(3))) void*)(Bs + chunk * 512), 16, 0, 0);
        }
        __syncthreads();
        #pragma unroll
        for (int i = 0; i < 2; ++i) {          // two K=32 substeps
            short8 av[8];
            #pragma unroll
            for (int mf = 0; mf < 8; ++mf) {
                int row = mf * 16 + (lane & 15);
                int sl = (4 * i + (lane >> 4)) ^ (row & 7);
                av[mf] = *reinterpret_cast<const short8*>(&As[row * 64 + sl * 8]);
            }
            #pragma unroll
            for (int t = 0; t < 5; ++t) {
                int rr = wave * 16 + (lane & 15);
                int sl = (4 * i + (lane >> 4)) ^ (rr & 7);
                short8 bv = *reinterpret_cast<const short8*>(&Bs[(t * 64 + rr) * 64 + sl * 8]);
                #pragma unroll
                for (int mf = 0; mf < 8; ++mf)
                    acc[mf][t] = __builtin_amdgcn_mfma_f32_16x16x32_bf16(av[mf], bv, acc[mf][t], 0, 0, 0);
            }
        }
        __syncthreads();
    }

    // epilogue: u = expm1(-q/1024) cubic; fused column stats
    const int col = n0 + wave * 16 + (lane & 15);
    const float lamc = lam[col], mmc = mm[col];
    const float4 vm = *reinterpret_cast<const float4*>(vmu + col * 4);
    float csum = 0.f, csq = 0.f;
    #pragma unroll
    for (int mf = 0; mf < 8; ++mf) {
        #pragma unroll
        for (int i = 0; i < 4; ++i) {
            int brow = m0 + mf * 16 + (lane >> 4) * 4 + i;
            float s0 = acc[mf][0][i];
            float p0 = acc[mf][1][i] - vm.x;
            float p1 = acc[mf][2][i] - vm.y;
            float p2 = acc[mf][3][i] - vm.z;
            float p3 = acc[mf][4][i] - vm.w;
            float q = lamc * (xx[brow] - 2.f * s0 + mmc)
                    + p0 * p0 + p1 * p1 + p2 * p2 + p3 * p3;
            float xq = q * (1.0f / 1024.0f);
            float u = -xq * (1.0f - xq * (0.5f - xq * 0.16666667f));  // expm1(-x)
            float ur;
            if (STORE_BF16) {
                ushortT ub = f2bf(u);
                Ub[(size_t)brow * ND + col] = ub;
                ur = bf2f(ub);
            } else {
                Uf[(size_t)brow * ND + col] = u;
                ur = u;
            }
            csum += ur; csq += ur * ur;
        }
    }
    csum += __shfl_xor(csum, 16); csum += __shfl_xor(csum, 32);
    csq  += __shfl_xor(csq, 16);  csq  += __shfl_xor(csq, 32);
    if (lane < 16) {
        atomicAdd(&sum[col], csum);
        atomicAdd(&sumsq[col], csq);
    }
}

// --- BN1 apply -> h (bf16) + post-round row norms (wave-per-row) -------------
// grid 1024 x 256 thr = 4096 waves; wave w = row w. No block barriers.
__global__ void bn_apply_h(const ushortT* __restrict__ U, const float* __restrict__ sum,
                           const float* __restrict__ sumsq, const float* __restrict__ g,
                           const float* __restrict__ beta, ushortT* __restrict__ hh,
                           float* __restrict__ xx2) {
    const int gid = blockIdx.x * 256 + threadIdx.x;
    const int row = gid >> 6, l = gid & 63;
    const ushortT* urow = U + (size_t)row * ND;
    ushortT* hrow = hh + (size_t)row * ND;
    float s = 0.f;
    #pragma unroll
    for (int j = 0; j < 4; ++j) {
        int c = (j * 64 + l) * 4;
        ushort4 uv = *reinterpret_cast<const ushort4*>(urow + c);
        float4 sv = *reinterpret_cast<const float4*>(sum + c);
        float4 qv = *reinterpret_cast<const float4*>(sumsq + c);
        float4 gv = *reinterpret_cast<const float4*>(g + c);
        float4 bv = *reinterpret_cast<const float4*>(beta + c);
        float ua[4] = {bf2f(uv.x), bf2f(uv.y), bf2f(uv.z), bf2f(uv.w)};
        float sa[4] = {sv.x, sv.y, sv.z, sv.w};
        float qa[4] = {qv.x, qv.y, qv.z, qv.w};
        float ga[4] = {gv.x, gv.y, gv.z, gv.w};
        float ba[4] = {bv.x, bv.y, bv.z, bv.w};
        ushortT hb[4];
        #pragma unroll
        for (int e = 0; e < 4; ++e) {
            float m = sa[e] * (1.0f / 4096.0f);
            float var = qa[e] * (1.0f / 4096.0f) - m * m;
            float a = rsqrtf(var + 1e-5f) * ga[e];
            float h = (ua[e] - m) * a + ba[e];
            hb[e] = f2bf(h);
            float hr = bf2f(hb[e]);
            s += hr * hr;
        }
        *reinterpret_cast<ushort4*>(hrow + c) = make_ushort4(hb[0], hb[1], hb[2], hb[3]);
    }
    s = wave_sum(s);
    if (l == 0) xx2[row] = s;
}

// --- BN2 apply + identity shortcut (wave-per-row) ----------------------------
__global__ void bn_apply_out(const float* __restrict__ U, const float* __restrict__ sum,
                             const float* __restrict__ sumsq, const float* __restrict__ g,
                             const float* __restrict__ beta, const float* __restrict__ x,
                             float* __restrict__ out) {
    const int gid = blockIdx.x * 256 + threadIdx.x;
    const int row = gid >> 6, l = gid & 63;
    const float* urow = U + (size_t)row * ND;
    const float* xrow = x + (size_t)row * ND;
    float* orow = out + (size_t)row * ND;
    #pragma unroll
    for (int j = 0; j < 4; ++j) {
        int c = (j * 64 + l) * 4;
        float4 uv = *reinterpret_cast<const float4*>(urow + c);
        float4 xv = *reinterpret_cast<const float4*>(xrow + c);
        float4 sv = *reinterpret_cast<const float4*>(sum + c);
        float4 qv = *reinterpret_cast<const float4*>(sumsq + c);
        float4 gv = *reinterpret_cast<const float4*>(g + c);
        float4 bv = *reinterpret_cast<const float4*>(beta + c);
        float4 ov;
        {
            float m = sv.x * (1.0f/4096.0f), var = qv.x * (1.0f/4096.0f) - m*m;
            float a = rsqrtf(var + 1e-5f) * gv.x; ov.x = (uv.x - m) * a + bv.x + xv.x;
        }
        {
            float m = sv.y * (1.0f/4096.0f), var = qv.y * (1.0f/4096.0f) - m*m;
            float a = rsqrtf(var + 1e-5f) * gv.y; ov.y = (uv.y - m) * a + bv.y + xv.y;
        }
        {
            float m = sv.z * (1.0f/4096.0f), var = qv.z * (1.0f/4096.0f) - m*m;
            float a = rsqrtf(var + 1e-5f) * gv.z; ov.z = (uv.z - m) * a + bv.z + xv.z;
        }
        {
            float m = sv.w * (1.0f/4096.0f), var = qv.w * (1.0f/4096.0f) - m*m;
            float a = rsqrtf(var + 1e-5f) * gv.w; ov.w = (uv.w - m) * a + bv.w + xv.w;
        }
        *reinterpret_cast<float4*>(orow + c) = ov;
    }
}

extern "C" void kernel_launch(void* const* d_in, const int* in_sizes, int n_in,
                              void* d_out, int out_size, void* d_ws, size_t ws_size,
                              hipStream_t stream) {
    const float* x    = (const float*)d_in[0];
    const float* mu1  = (const float*)d_in[1];
    const float* lam1 = (const float*)d_in[2];
    const float* v1   = (const float*)d_in[3];
    const float* g1   = (const float*)d_in[4];
    const float* b1   = (const float*)d_in[5];
    const float* mu2  = (const float*)d_in[6];
    const float* lam2 = (const float*)d_in[7];
    const float* v2   = (const float*)d_in[8];
    const float* g2   = (const float*)d_in[9];
    const float* b2   = (const float*)d_in[10];
    float* out = (float*)d_out;
    char* ws = (char*)d_ws;
    const size_t MB = 1024 * 1024;

    // workspace layout (lifetime-overlapped):
    // [0,8)MB xh ; [8,18)MB W1 ; U2(f32,16MB) aliases [0,16) after gemm1 retires xh/W1
    // [18,26)MB hh ; [26,36)MB W2 ; [36,44)MB U1(bf16) ; [44MB,..) stats
    ushortT* xh  = (ushortT*)(ws + 0);
    ushortT* W1  = (ushortT*)(ws + 8 * MB);
    float*   U2  = (float*)  (ws + 0);
    ushortT* hh  = (ushortT*)(ws + 18 * MB);
    ushortT* W2  = (ushortT*)(ws + 26 * MB);
    ushortT* U1  = (ushortT*)(ws + 36 * MB);
    char* st = ws + 44 * MB;
    float* xx1    = (float*)(st + 0);
    float* xx2    = (float*)(st + 16384);
    float* mm1    = (float*)(st + 32768);
    float* mm2    = (float*)(st + 36864);
    float* vmu1   = (float*)(st + 40960);
    float* vmu2   = (float*)(st + 57344);
    float* sum1   = (float*)(st + 73728);   // sum1,sumsq1,sum2,sumsq2 contiguous 16KB
    float* sumsq1 = (float*)(st + 77824);
    float* sum2   = (float*)(st + 81920);
    float* sumsq2 = (float*)(st + 86016);

    const size_t needed = 44 * MB + 90112;
    if (ws_size < needed) return;

    prep_all<<<3584, 256, 0, stream>>>(x, mu1, v1, mu2, v2, xh, W1, W2,
                                       xx1, mm1, vmu1, mm2, vmu2, sum1);

    gemm_hmu<1><<<512, 256, 0, stream>>>(xh, W1, xx1, mm1, vmu1, lam1,
                                         U1, nullptr, sum1, sumsq1);
    bn_apply_h<<<1024, 256, 0, stream>>>(U1, sum1, sumsq1, g1, b1, hh, xx2);

    gemm_hmu<0><<<512, 256, 0, stream>>>(hh, W2, xx2, mm2, vmu2, lam2,
                                         nullptr, U2, sum2, sumsq2);
    bn_apply_out<<<1024, 256, 0, stream>>>(U2, sum2, sumsq2, g2, b2, x, out);
}